// Round 10
// baseline (132.153 us; speedup 1.0000x reference)
//
#include <hip/hip_runtime.h>
#include <math.h>

#define BB 1024
#define DD 128
#define QQ 65536
#define CHUNK 32
#define THREADS 256
#define COLS_PER_BLOCK 256
#define F2G (BB / COLS_PER_BLOCK)   // 4
#define NSLICES 512
#define SROWS (QQ / NSLICES)        // 128
#define NCHUNKS (SROWS / CHUNK)     // 4
#define INV_T 14.285714285714286f
#define SCALE 20.609929155556627f   // (1/T) * log2(e)
#define LN2F 0.6931471805599453f

typedef short short8 __attribute__((ext_vector_type(8)));
typedef float f32x4  __attribute__((ext_vector_type(4)));
typedef unsigned short us4 __attribute__((ext_vector_type(4)));

static __device__ __forceinline__ float fast_exp2(float x) {
    float r;
    asm("v_exp_f32 %0, %1" : "=v"(r) : "v"(x));
    return r;
}

static __device__ __forceinline__ unsigned short bf16rne(float f) {
    union { float f; unsigned u; } v; v.f = f;
    unsigned r = (v.u + 0x7FFFu + ((v.u >> 16) & 1u)) >> 16;
    return (unsigned short)r;
}

static __device__ __forceinline__ short8 pack8s(float4 x, float4 y) { // * SCALE
    short8 r;
    r[0]=(short)bf16rne(x.x*SCALE); r[1]=(short)bf16rne(x.y*SCALE);
    r[2]=(short)bf16rne(x.z*SCALE); r[3]=(short)bf16rne(x.w*SCALE);
    r[4]=(short)bf16rne(y.x*SCALE); r[5]=(short)bf16rne(y.y*SCALE);
    r[6]=(short)bf16rne(y.z*SCALE); r[7]=(short)bf16rne(y.w*SCALE);
    return r;
}
static __device__ __forceinline__ short8 pack8(float4 x, float4 y) { // unscaled
    short8 r;
    r[0]=(short)bf16rne(x.x); r[1]=(short)bf16rne(x.y);
    r[2]=(short)bf16rne(x.z); r[3]=(short)bf16rne(x.w);
    r[4]=(short)bf16rne(y.x); r[5]=(short)bf16rne(y.y);
    r[6]=(short)bf16rne(y.z); r[7]=(short)bf16rne(y.w);
    return r;
}

// ---------- K0: cnt histogram, srr dots, f2bf (scaled bf16) ----------
__global__ __launch_bounds__(256)
void k0_prep(const float* __restrict__ features, const int* __restrict__ labels,
             const int* __restrict__ queue_labels,
             int* __restrict__ cnt, float* __restrict__ srr, unsigned short* f2bf)
{
    int t = blockIdx.x * 256 + threadIdx.x;          // grid 256x256 = 65536
    {
        int lab = (t < BB) ? labels[t] : queue_labels[t - BB];
        atomicAdd(&cnt[lab], 1);
    }
    int r = t >> 6, lane = t & 63;                   // one wave per batch row
    float2 a = reinterpret_cast<const float2*>(features + (size_t)r * 2 * DD + DD)[lane];
    float2 b = reinterpret_cast<const float2*>(features + (size_t)r * 2 * DD)[lane];
    float p = a.x * b.x + a.y * b.y;
#pragma unroll
    for (int off = 32; off > 0; off >>= 1) p += __shfl_xor(p, off);
    if (lane == 0) srr[r] = p;
    if (f2bf) {
        unsigned int packed = (unsigned int)bf16rne(a.x * SCALE)
                            | ((unsigned int)bf16rne(a.y * SCALE) << 16);
        reinterpret_cast<unsigned int*>(f2bf)[(size_t)r * (DD / 2) + lane] = packed;
    }
}

// ---------- K1: pure streaming convert: qbf (linear bf16 queue_new) + qlabn ----------
__global__ __launch_bounds__(256)
void k1_conv(const float* __restrict__ features, const int* __restrict__ labels,
             const float* __restrict__ queue, const int* __restrict__ queue_labels,
             unsigned short* __restrict__ qbf, int* __restrict__ qlabn)
{
    const int t = blockIdx.x * 256 + threadIdx.x;
    if (blockIdx.x < 256) {
        int j = t;  // t < 65536
        qlabn[j] = (j < BB) ? labels[j] : queue_labels[j - BB];
    }
#pragma unroll
    for (int k = 0; k < 16; ++k) {
        int u = k * 131072 + t;          // us4 index, 2M total
        int e = u * 4;                   // element index
        int row = e >> 7;
        const float* src = (row < BB) ? (features + (size_t)row * 2 * DD + (e & 127))
                                      : (queue + ((size_t)e - (size_t)BB * DD));
        float4 v = *reinterpret_cast<const float4*>(src);
        us4 pk;
        pk[0] = bf16rne(v.x); pk[1] = bf16rne(v.y);
        pk[2] = bf16rne(v.z); pk[3] = bf16rne(v.w);
        *reinterpret_cast<us4*>(qbf + (size_t)e) = pk;
    }
}

// ---------- main: r5 structure — reg-staged LDS dbuf, 4 waves x 64 cols ----------
template<int PRE>
__global__ __launch_bounds__(THREADS)
void supcon_main(const float* __restrict__ features, const int* __restrict__ labels,
                 const float* __restrict__ queue, const int* __restrict__ queue_labels,
                 const unsigned short* __restrict__ qbf, const int* __restrict__ qlabn,
                 const unsigned short* __restrict__ f2bf,
                 float* __restrict__ rowacc)
{
    __shared__ int4 ldsbuf[2][512];   // 2 x 8KB bf16 A-chunks [32][128], swizzled

    const int tid = threadIdx.x;
    const int l = tid & 63, w = tid >> 6;
    const int bid = blockIdx.x;
    const int slice = bid & (NSLICES - 1);   // bid%8 == slice%8: slice pinned to one XCD
    const int f2g = bid >> 9;                // bid / NSLICES
    const int colbase = f2g * COLS_PER_BLOCK + w * 64;

    // stationary B operand: 4x16 f2 cols, pre-scaled bf16
    short8 bf[4][4];
    int mylab[4];
#pragma unroll
    for (int b = 0; b < 4; ++b) {
        int r = colbase + b * 16 + (l & 15);
        mylab[b] = labels[r];
        if (PRE) {
            const unsigned short* fp = f2bf + (size_t)r * DD + ((l >> 4) * 8);
#pragma unroll
            for (int kk = 0; kk < 4; ++kk)
                bf[b][kk] = *reinterpret_cast<const short8*>(fp + kk * 32);
        } else {
            const float* fp = features + (size_t)r * 2 * DD + DD + ((l >> 4) * 8);
#pragma unroll
            for (int kk = 0; kk < 4; ++kk) {
                float4 x = *reinterpret_cast<const float4*>(fp + kk * 32);
                float4 y = *reinterpret_cast<const float4*>(fp + kk * 32 + 4);
                bf[b][kk] = pack8s(x, y);
            }
        }
    }

    float tot[4]  = {0.f,0.f,0.f,0.f};
    float pose[4] = {0.f,0.f,0.f,0.f};
    float psum[4] = {0.f,0.f,0.f,0.f};

    const int srow = tid >> 3, sseg = tid & 7;
    const int swzs = (srow & 7) << 4;
    const int j0base = slice * SROWS;

    // prologue: stage chunk 0
    {
        int j = j0base + srow;
        char* base = (char*)&ldsbuf[0][0] + srow * 256;
        int cb0 = (sseg * 32) ^ swzs;
        if (PRE) {
            const short8* src = reinterpret_cast<const short8*>(
                qbf + (size_t)j * DD + sseg * 16);
            *reinterpret_cast<short8*>(base + cb0)        = src[0];
            *reinterpret_cast<short8*>(base + (cb0 ^ 16)) = src[1];
        } else {
            const float* src = ((j < BB) ? (features + (size_t)j * 2 * DD)
                                         : (queue + (size_t)(j - BB) * DD)) + sseg * 16;
            float4 p0 = reinterpret_cast<const float4*>(src)[0];
            float4 p1 = reinterpret_cast<const float4*>(src)[1];
            float4 p2 = reinterpret_cast<const float4*>(src)[2];
            float4 p3 = reinterpret_cast<const float4*>(src)[3];
            *reinterpret_cast<short8*>(base + cb0)        = pack8(p0, p1);
            *reinterpret_cast<short8*>(base + (cb0 ^ 16)) = pack8(p2, p3);
        }
    }

    int cur = 0;
    for (int c = 0; c < NCHUNKS; ++c) {
        __syncthreads();
        const int cj0 = j0base + c * CHUNK;
        const bool havenext = (c + 1 < NCHUNKS);

        // issue next chunk's loads early (T14)
        short8 nlo, nhi;
        float4 p0, p1, p2, p3;
        if (havenext) {
            int j = cj0 + CHUNK + srow;
            if (PRE) {
                const short8* src = reinterpret_cast<const short8*>(
                    qbf + (size_t)j * DD + sseg * 16);
                nlo = src[0]; nhi = src[1];
            } else {
                const float* src = ((j < BB) ? (features + (size_t)j * 2 * DD)
                                             : (queue + (size_t)(j - BB) * DD)) + sseg * 16;
                p0 = reinterpret_cast<const float4*>(src)[0];
                p1 = reinterpret_cast<const float4*>(src)[1];
                p2 = reinterpret_cast<const float4*>(src)[2];
                p3 = reinterpret_cast<const float4*>(src)[3];
            }
        }

        // compute from buf[cur]
        const char* abase = (const char*)&ldsbuf[cur][0];
#pragma unroll
        for (int t2 = 0; t2 < 2; ++t2) {
            const int row = t2 * 16 + (l & 15);
            const char* rbase = abase + row * 256;
            const int g16 = (l >> 4) * 16;
            const int swz = (row & 7) << 4;
            const int j0 = cj0 + t2 * 16 + ((l >> 4) << 2);

            int4 ql4;
            if (PRE) ql4 = *reinterpret_cast<const int4*>(qlabn + j0);
            else ql4 = (j0 < BB) ? *reinterpret_cast<const int4*>(labels + j0)
                                 : *reinterpret_cast<const int4*>(queue_labels + (j0 - BB));
            const int* ql = reinterpret_cast<const int*>(&ql4);

            f32x4 acc[4];
#pragma unroll
            for (int b = 0; b < 4; ++b) acc[b] = f32x4{0.f,0.f,0.f,0.f};
#pragma unroll
            for (int kk = 0; kk < 4; ++kk) {
                short8 a = *reinterpret_cast<const short8*>(rbase + ((kk * 64 + g16) ^ swz));
#pragma unroll
                for (int b = 0; b < 4; ++b)
                    acc[b] = __builtin_amdgcn_mfma_f32_16x16x32_bf16(a, bf[b][kk], acc[b], 0, 0, 0);
            }
#pragma unroll
            for (int b = 0; b < 4; ++b) {
#pragma unroll
                for (int reg = 0; reg < 4; ++reg) {
                    float a = acc[b][reg];
                    float e = fast_exp2(a);             // a = s * log2(e)
                    float pf = (ql[reg] == mylab[b]) ? 1.0f : 0.0f;
                    tot[b]  += e;
                    pose[b]  = fmaf(pf, e, pose[b]);
                    psum[b]  = fmaf(pf, a, psum[b]);
                }
            }
        }

        // write next chunk into other buffer
        if (havenext) {
            char* base = (char*)&ldsbuf[cur ^ 1][0] + srow * 256;
            int cb0 = (sseg * 32) ^ swzs;
            if (PRE) {
                *reinterpret_cast<short8*>(base + cb0)        = nlo;
                *reinterpret_cast<short8*>(base + (cb0 ^ 16)) = nhi;
            } else {
                *reinterpret_cast<short8*>(base + cb0)        = pack8(p0, p1);
                *reinterpret_cast<short8*>(base + (cb0 ^ 16)) = pack8(p2, p3);
            }
            cur ^= 1;
        }
    }

#pragma unroll
    for (int b = 0; b < 4; ++b) {
#pragma unroll
        for (int off = 16; off <= 32; off <<= 1) {
            tot[b]  += __shfl_xor(tot[b],  off);
            pose[b] += __shfl_xor(pose[b], off);
            psum[b] += __shfl_xor(psum[b], off);
        }
    }
    if (l < 16) {
#pragma unroll
        for (int b = 0; b < 4; ++b) {
            float* d = rowacc + (size_t)(colbase + b * 16 + l) * 4;
            atomicAdd(d + 0, tot[b]);
            atomicAdd(d + 1, pose[b]);
            atomicAdd(d + 2, psum[b]);
        }
    }
}

// ---------- finish: per-row log terms, two scalars, last block writes out ----------
__global__ __launch_bounds__(256)
void f_finish(const float* __restrict__ rowacc, const float* __restrict__ srr,
              const int* __restrict__ cnt, const int* __restrict__ labels,
              float* __restrict__ scal, int* __restrict__ ticket,
              float* __restrict__ out)
{
    __shared__ float red[4][2];
    const int r = blockIdx.x * 256 + threadIdx.x;
    const int wv = threadIdx.x >> 6, lane = threadIdx.x & 63;

    float4 v = reinterpret_cast<const float4*>(rowacc)[r];
    float tot = v.x, pose = v.y, ps = v.z;
    float srow = srr[r] * INV_T;                 // exact diag logit
    float trip = srow - logf(tot - expf(srow));
    float wgt  = 1.f / (float)(cnt[labels[r]] - 1);
    float mlpp = (ps * LN2F - srow) * wgt - logf(tot - pose);

#pragma unroll
    for (int off = 32; off > 0; off >>= 1) {
        trip += __shfl_xor(trip, off);
        mlpp += __shfl_xor(mlpp, off);
    }
    if (lane == 0) { red[wv][0] = trip; red[wv][1] = mlpp; }
    __syncthreads();
    if (threadIdx.x == 0) {
        atomicAdd(&scal[0], red[0][0] + red[1][0] + red[2][0] + red[3][0]);
        atomicAdd(&scal[1], red[0][1] + red[1][1] + red[2][1] + red[3][1]);
        __threadfence();
        int old = atomicAdd(ticket, 1);
        if (old == 3) {
            float aT = atomicAdd(&scal[0], 0.f);
            float aM = atomicAdd(&scal[1], 0.f);
            float selfl  = -aT / (float)BB;
            float classl = -aM / (float)BB;
            out[0] = 0.5f * (selfl + classl);
            out[1] = selfl;
            out[2] = classl;
        }
    }
}

extern "C" void kernel_launch(void* const* d_in, const int* in_sizes, int n_in,
                              void* d_out, int out_size, void* d_ws, size_t ws_size,
                              hipStream_t stream)
{
    const float* features     = (const float*)d_in[0];
    const int*   labels       = (const int*)  d_in[1];
    const float* queue        = (const float*)d_in[2];
    const int*   queue_labels = (const int*)  d_in[3];
    char* ws = (char*)d_ws;

    // ws layout: [zeroed: cnt 4096 | scal 128 | ticket 128 | rowacc 16384]
    //            srr 4096 | f2bf 256KB | qbf 16MB | qlabn 256KB
    const size_t cnt_off    = 0;
    const size_t scal_off   = 4096;
    const size_t ticket_off = 4096 + 128;
    const size_t rowacc_off = 4096 + 256;
    const size_t zero_sz    = rowacc_off + 16384;
    const size_t srr_off    = zero_sz;
    const size_t f2bf_off   = srr_off + 4096;
    const size_t f2bf_sz    = (size_t)BB * DD * 2;        // 256 KB
    const size_t qbf_off    = f2bf_off + f2bf_sz;
    const size_t qbf_sz     = (size_t)QQ * DD * 2;        // 16 MB
    const size_t qlabn_off  = qbf_off + qbf_sz;
    const size_t total_pre  = qlabn_off + (size_t)QQ * 4;

    const bool pre = ws_size >= total_pre;

    int*   cnt    = (int*)(ws + cnt_off);
    float* scal   = (float*)(ws + scal_off);
    int*   ticket = (int*)(ws + ticket_off);
    float* rowacc = (float*)(ws + rowacc_off);
    float* srr    = (float*)(ws + srr_off);
    unsigned short* f2bf = pre ? (unsigned short*)(ws + f2bf_off) : nullptr;
    unsigned short* qbf  = pre ? (unsigned short*)(ws + qbf_off) : nullptr;
    int* qlabn           = pre ? (int*)(ws + qlabn_off) : nullptr;

    hipMemsetAsync(ws, 0, zero_sz, stream);

    k0_prep<<<dim3(256), dim3(256), 0, stream>>>(
        features, labels, queue_labels, cnt, srr, f2bf);

    if (pre)
        k1_conv<<<dim3(512), dim3(256), 0, stream>>>(
            features, labels, queue, queue_labels, qbf, qlabn);

    dim3 grid(F2G * NSLICES);   // 2048 blocks
    if (pre)
        supcon_main<1><<<grid, dim3(THREADS), 0, stream>>>(
            features, labels, queue, queue_labels, qbf, qlabn, f2bf, rowacc);
    else
        supcon_main<0><<<grid, dim3(THREADS), 0, stream>>>(
            features, labels, queue, queue_labels, qbf, qlabn, f2bf, rowacc);

    f_finish<<<dim3(4), dim3(256), 0, stream>>>(
        rowacc, srr, cnt, labels, scal, ticket, (float*)d_out);
}

// Round 11
// 103.524 us; speedup vs baseline: 1.2765x; 1.2765x over previous
//
#include <hip/hip_runtime.h>
#include <math.h>

#define BB 1024
#define DD 128
#define QQ 65536
#define CHUNK 32
#define THREADS 256
#define COLS_PER_BLOCK 256
#define F2G (BB / COLS_PER_BLOCK)   // 4
#define NSLICES 256
#define SROWS (QQ / NSLICES)        // 256
#define NCHUNKS (SROWS / CHUNK)     // 8
#define INV_T 14.285714285714286f
#define SCALE 20.609929155556627f   // (1/T) * log2(e)
#define LN2F 0.6931471805599453f

typedef short short8 __attribute__((ext_vector_type(8)));
typedef float f32x4  __attribute__((ext_vector_type(4)));
typedef unsigned short us4 __attribute__((ext_vector_type(4)));

#if __has_builtin(__builtin_amdgcn_exp2f)
#define EXP2F(x) __builtin_amdgcn_exp2f(x)
#else
#define EXP2F(x) exp2f(x)
#endif

static __device__ __forceinline__ unsigned short bf16rne(float f) {
    union { float f; unsigned u; } v; v.f = f;
    unsigned r = (v.u + 0x7FFFu + ((v.u >> 16) & 1u)) >> 16;
    return (unsigned short)r;
}

static __device__ __forceinline__ short8 pack8s(float4 x, float4 y) { // * SCALE
    short8 r;
    r[0]=(short)bf16rne(x.x*SCALE); r[1]=(short)bf16rne(x.y*SCALE);
    r[2]=(short)bf16rne(x.z*SCALE); r[3]=(short)bf16rne(x.w*SCALE);
    r[4]=(short)bf16rne(y.x*SCALE); r[5]=(short)bf16rne(y.y*SCALE);
    r[6]=(short)bf16rne(y.z*SCALE); r[7]=(short)bf16rne(y.w*SCALE);
    return r;
}
static __device__ __forceinline__ short8 pack8(float4 x, float4 y) { // unscaled
    short8 r;
    r[0]=(short)bf16rne(x.x); r[1]=(short)bf16rne(x.y);
    r[2]=(short)bf16rne(x.z); r[3]=(short)bf16rne(x.w);
    r[4]=(short)bf16rne(y.x); r[5]=(short)bf16rne(y.y);
    r[6]=(short)bf16rne(y.z); r[7]=(short)bf16rne(y.w);
    return r;
}

// ---------- K0: cnt histogram, srr dots, f2bf (scaled bf16) ----------
__global__ __launch_bounds__(256)
void k0_prep(const float* __restrict__ features, const int* __restrict__ labels,
             const int* __restrict__ queue_labels,
             int* __restrict__ cnt, float* __restrict__ srr, unsigned short* f2bf)
{
    int t = blockIdx.x * 256 + threadIdx.x;          // grid 256x256 = 65536
    {
        int lab = (t < BB) ? labels[t] : queue_labels[t - BB];
        atomicAdd(&cnt[lab], 1);
    }
    int r = t >> 6, lane = t & 63;                   // one wave per batch row
    float2 a = reinterpret_cast<const float2*>(features + (size_t)r * 2 * DD + DD)[lane];
    float2 b = reinterpret_cast<const float2*>(features + (size_t)r * 2 * DD)[lane];
    float p = a.x * b.x + a.y * b.y;
#pragma unroll
    for (int off = 32; off > 0; off >>= 1) p += __shfl_xor(p, off);
    if (lane == 0) srr[r] = p;
    if (f2bf) {
        unsigned int packed = (unsigned int)bf16rne(a.x * SCALE)
                            | ((unsigned int)bf16rne(a.y * SCALE) << 16);
        reinterpret_cast<unsigned int*>(f2bf)[(size_t)r * (DD / 2) + lane] = packed;
    }
}

// ---------- K1: pure streaming convert: qbf (linear bf16 queue_new) + qlabn ----------
__global__ __launch_bounds__(256)
void k1_conv(const float* __restrict__ features, const int* __restrict__ labels,
             const float* __restrict__ queue, const int* __restrict__ queue_labels,
             unsigned short* __restrict__ qbf, int* __restrict__ qlabn)
{
    const int t = blockIdx.x * 256 + threadIdx.x;
    if (blockIdx.x < 256) {
        int j = t;  // t < 65536
        qlabn[j] = (j < BB) ? labels[j] : queue_labels[j - BB];
    }
#pragma unroll
    for (int k = 0; k < 16; ++k) {
        int u = k * 131072 + t;          // us4 index, 2M total
        int e = u * 4;                   // element index
        int row = e >> 7;
        const float* src = (row < BB) ? (features + (size_t)row * 2 * DD + (e & 127))
                                      : (queue + ((size_t)e - (size_t)BB * DD));
        float4 v = *reinterpret_cast<const float4*>(src);
        us4 pk;
        pk[0] = bf16rne(v.x); pk[1] = bf16rne(v.y);
        pk[2] = bf16rne(v.z); pk[3] = bf16rne(v.w);
        *reinterpret_cast<us4*>(qbf + (size_t)e) = pk;
    }
}

// ---------- main: r5 structure verbatim; EXP2F intrinsic; rowacc atomic ending ----------
template<int PRE>
__global__ __launch_bounds__(THREADS)
void supcon_main(const float* __restrict__ features, const int* __restrict__ labels,
                 const float* __restrict__ queue, const int* __restrict__ queue_labels,
                 const unsigned short* __restrict__ qbf, const int* __restrict__ qlabn,
                 const unsigned short* __restrict__ f2bf,
                 float* __restrict__ rowacc)
{
    __shared__ int4 ldsbuf[2][512];   // 2 x 8KB bf16 A-chunks [32][128], swizzled

    const int tid = threadIdx.x;
    const int l = tid & 63, w = tid >> 6;
    const int bid = blockIdx.x;
    const int slice = bid & (NSLICES - 1);   // bid%8 == slice%8: slice pinned to one XCD
    const int f2g = bid >> 8;
    const int colbase = f2g * COLS_PER_BLOCK + w * 64;

    // stationary B operand: 4x16 f2 cols, pre-scaled bf16
    short8 bf[4][4];
    int mylab[4];
#pragma unroll
    for (int b = 0; b < 4; ++b) {
        int r = colbase + b * 16 + (l & 15);
        mylab[b] = labels[r];
        if (PRE) {
            const unsigned short* fp = f2bf + (size_t)r * DD + ((l >> 4) * 8);
#pragma unroll
            for (int kk = 0; kk < 4; ++kk)
                bf[b][kk] = *reinterpret_cast<const short8*>(fp + kk * 32);
        } else {
            const float* fp = features + (size_t)r * 2 * DD + DD + ((l >> 4) * 8);
#pragma unroll
            for (int kk = 0; kk < 4; ++kk) {
                float4 x = *reinterpret_cast<const float4*>(fp + kk * 32);
                float4 y = *reinterpret_cast<const float4*>(fp + kk * 32 + 4);
                bf[b][kk] = pack8s(x, y);
            }
        }
    }

    float tot[4]  = {0.f,0.f,0.f,0.f};
    float pose[4] = {0.f,0.f,0.f,0.f};
    float psum[4] = {0.f,0.f,0.f,0.f};

    const int srow = tid >> 3, sseg = tid & 7;
    const int swzs = (srow & 7) << 4;
    const int j0base = slice * SROWS;

    // prologue: stage chunk 0
    {
        int j = j0base + srow;
        char* base = (char*)&ldsbuf[0][0] + srow * 256;
        int cb0 = (sseg * 32) ^ swzs;
        if (PRE) {
            const short8* src = reinterpret_cast<const short8*>(
                qbf + (size_t)j * DD + sseg * 16);
            *reinterpret_cast<short8*>(base + cb0)        = src[0];
            *reinterpret_cast<short8*>(base + (cb0 ^ 16)) = src[1];
        } else {
            const float* src = ((j < BB) ? (features + (size_t)j * 2 * DD)
                                         : (queue + (size_t)(j - BB) * DD)) + sseg * 16;
            float4 p0 = reinterpret_cast<const float4*>(src)[0];
            float4 p1 = reinterpret_cast<const float4*>(src)[1];
            float4 p2 = reinterpret_cast<const float4*>(src)[2];
            float4 p3 = reinterpret_cast<const float4*>(src)[3];
            *reinterpret_cast<short8*>(base + cb0)        = pack8(p0, p1);
            *reinterpret_cast<short8*>(base + (cb0 ^ 16)) = pack8(p2, p3);
        }
    }

    int cur = 0;
    for (int c = 0; c < NCHUNKS; ++c) {
        __syncthreads();
        const int cj0 = j0base + c * CHUNK;
        const bool havenext = (c + 1 < NCHUNKS);

        // issue next chunk's loads early (T14)
        short8 nlo, nhi;
        float4 p0, p1, p2, p3;
        if (havenext) {
            int j = cj0 + CHUNK + srow;
            if (PRE) {
                const short8* src = reinterpret_cast<const short8*>(
                    qbf + (size_t)j * DD + sseg * 16);
                nlo = src[0]; nhi = src[1];
            } else {
                const float* src = ((j < BB) ? (features + (size_t)j * 2 * DD)
                                             : (queue + (size_t)(j - BB) * DD)) + sseg * 16;
                p0 = reinterpret_cast<const float4*>(src)[0];
                p1 = reinterpret_cast<const float4*>(src)[1];
                p2 = reinterpret_cast<const float4*>(src)[2];
                p3 = reinterpret_cast<const float4*>(src)[3];
            }
        }

        // compute from buf[cur]
        const char* abase = (const char*)&ldsbuf[cur][0];
#pragma unroll
        for (int t2 = 0; t2 < 2; ++t2) {
            const int row = t2 * 16 + (l & 15);
            const char* rbase = abase + row * 256;
            const int g16 = (l >> 4) * 16;
            const int swz = (row & 7) << 4;
            const int j0 = cj0 + t2 * 16 + ((l >> 4) << 2);

            int4 ql4;
            if (PRE) ql4 = *reinterpret_cast<const int4*>(qlabn + j0);
            else ql4 = (j0 < BB) ? *reinterpret_cast<const int4*>(labels + j0)
                                 : *reinterpret_cast<const int4*>(queue_labels + (j0 - BB));
            const int* ql = reinterpret_cast<const int*>(&ql4);

            f32x4 acc[4];
#pragma unroll
            for (int b = 0; b < 4; ++b) acc[b] = f32x4{0.f,0.f,0.f,0.f};
#pragma unroll
            for (int kk = 0; kk < 4; ++kk) {
                short8 a = *reinterpret_cast<const short8*>(rbase + ((kk * 64 + g16) ^ swz));
#pragma unroll
                for (int b = 0; b < 4; ++b)
                    acc[b] = __builtin_amdgcn_mfma_f32_16x16x32_bf16(a, bf[b][kk], acc[b], 0, 0, 0);
            }
#pragma unroll
            for (int b = 0; b < 4; ++b) {
#pragma unroll
                for (int reg = 0; reg < 4; ++reg) {
                    float a = acc[b][reg];
                    float e = EXP2F(a);                 // a = s * log2(e)
                    bool pos = (ql[reg] == mylab[b]);
                    tot[b]  += e;
                    pose[b] += pos ? e : 0.f;
                    psum[b] += pos ? a : 0.f;
                }
            }
        }

        // write next chunk into other buffer
        if (havenext) {
            char* base = (char*)&ldsbuf[cur ^ 1][0] + srow * 256;
            int cb0 = (sseg * 32) ^ swzs;
            if (PRE) {
                *reinterpret_cast<short8*>(base + cb0)        = nlo;
                *reinterpret_cast<short8*>(base + (cb0 ^ 16)) = nhi;
            } else {
                *reinterpret_cast<short8*>(base + cb0)        = pack8(p0, p1);
                *reinterpret_cast<short8*>(base + (cb0 ^ 16)) = pack8(p2, p3);
            }
            cur ^= 1;
        }
    }

#pragma unroll
    for (int b = 0; b < 4; ++b) {
#pragma unroll
        for (int off = 16; off <= 32; off <<= 1) {
            tot[b]  += __shfl_xor(tot[b],  off);
            pose[b] += __shfl_xor(pose[b], off);
            psum[b] += __shfl_xor(psum[b], off);
        }
    }
    if (l < 16) {
#pragma unroll
        for (int b = 0; b < 4; ++b) {
            float* d = rowacc + (size_t)(colbase + b * 16 + l) * 4;
            atomicAdd(d + 0, tot[b]);
            atomicAdd(d + 1, pose[b]);
            atomicAdd(d + 2, psum[b]);
        }
    }
}

// ---------- finish: per-row log terms, two scalars, last block writes out ----------
__global__ __launch_bounds__(256)
void f_finish(const float* __restrict__ rowacc, const float* __restrict__ srr,
              const int* __restrict__ cnt, const int* __restrict__ labels,
              float* __restrict__ scal, int* __restrict__ ticket,
              float* __restrict__ out)
{
    __shared__ float red[4][2];
    const int r = blockIdx.x * 256 + threadIdx.x;
    const int wv = threadIdx.x >> 6, lane = threadIdx.x & 63;

    float4 v = reinterpret_cast<const float4*>(rowacc)[r];
    float tot = v.x, pose = v.y, ps = v.z;
    float srow = srr[r] * INV_T;                 // exact diag logit
    float trip = srow - logf(tot - expf(srow));
    float wgt  = 1.f / (float)(cnt[labels[r]] - 1);
    float mlpp = (ps * LN2F - srow) * wgt - logf(tot - pose);

#pragma unroll
    for (int off = 32; off > 0; off >>= 1) {
        trip += __shfl_xor(trip, off);
        mlpp += __shfl_xor(mlpp, off);
    }
    if (lane == 0) { red[wv][0] = trip; red[wv][1] = mlpp; }
    __syncthreads();
    if (threadIdx.x == 0) {
        atomicAdd(&scal[0], red[0][0] + red[1][0] + red[2][0] + red[3][0]);
        atomicAdd(&scal[1], red[0][1] + red[1][1] + red[2][1] + red[3][1]);
        __threadfence();
        int old = atomicAdd(ticket, 1);
        if (old == 3) {
            float aT = atomicAdd(&scal[0], 0.f);
            float aM = atomicAdd(&scal[1], 0.f);
            float selfl  = -aT / (float)BB;
            float classl = -aM / (float)BB;
            out[0] = 0.5f * (selfl + classl);
            out[1] = selfl;
            out[2] = classl;
        }
    }
}

extern "C" void kernel_launch(void* const* d_in, const int* in_sizes, int n_in,
                              void* d_out, int out_size, void* d_ws, size_t ws_size,
                              hipStream_t stream)
{
    const float* features     = (const float*)d_in[0];
    const int*   labels       = (const int*)  d_in[1];
    const float* queue        = (const float*)d_in[2];
    const int*   queue_labels = (const int*)  d_in[3];
    char* ws = (char*)d_ws;

    // ws layout: [zeroed: cnt 4096 | scal 128 | ticket 128 | rowacc 16384]
    //            srr 4096 | f2bf 256KB | qbf 16MB | qlabn 256KB
    const size_t cnt_off    = 0;
    const size_t scal_off   = 4096;
    const size_t ticket_off = 4096 + 128;
    const size_t rowacc_off = 4096 + 256;
    const size_t zero_sz    = rowacc_off + 16384;
    const size_t srr_off    = zero_sz;
    const size_t f2bf_off   = srr_off + 4096;
    const size_t f2bf_sz    = (size_t)BB * DD * 2;        // 256 KB
    const size_t qbf_off    = f2bf_off + f2bf_sz;
    const size_t qbf_sz     = (size_t)QQ * DD * 2;        // 16 MB
    const size_t qlabn_off  = qbf_off + qbf_sz;
    const size_t total_pre  = qlabn_off + (size_t)QQ * 4;

    const bool pre = ws_size >= total_pre;

    int*   cnt    = (int*)(ws + cnt_off);
    float* scal   = (float*)(ws + scal_off);
    int*   ticket = (int*)(ws + ticket_off);
    float* rowacc = (float*)(ws + rowacc_off);
    float* srr    = (float*)(ws + srr_off);
    unsigned short* f2bf = pre ? (unsigned short*)(ws + f2bf_off) : nullptr;
    unsigned short* qbf  = pre ? (unsigned short*)(ws + qbf_off) : nullptr;
    int* qlabn           = pre ? (int*)(ws + qlabn_off) : nullptr;

    hipMemsetAsync(ws, 0, zero_sz, stream);

    k0_prep<<<dim3(256), dim3(256), 0, stream>>>(
        features, labels, queue_labels, cnt, srr, f2bf);

    if (pre)
        k1_conv<<<dim3(512), dim3(256), 0, stream>>>(
            features, labels, queue, queue_labels, qbf, qlabn);

    dim3 grid(F2G * NSLICES);   // 1024 blocks
    if (pre)
        supcon_main<1><<<grid, dim3(THREADS), 0, stream>>>(
            features, labels, queue, queue_labels, qbf, qlabn, f2bf, rowacc);
    else
        supcon_main<0><<<grid, dim3(THREADS), 0, stream>>>(
            features, labels, queue, queue_labels, qbf, qlabn, f2bf, rowacc);

    f_finish<<<dim3(4), dim3(256), 0, stream>>>(
        rowacc, srr, cnt, labels, scal, ticket, (float*)d_out);
}

// Round 12
// 98.341 us; speedup vs baseline: 1.3438x; 1.0527x over previous
//
#include <hip/hip_runtime.h>
#include <math.h>

#define BB 1024
#define DD 128
#define QQ 65536
#define CHUNK 32
#define THREADS 256
#define COLS_PER_BLOCK 256
#define F2G (BB / COLS_PER_BLOCK)   // 4
#define NSLICES 256
#define INV_T 14.285714285714286f
#define SCALE 20.609929155556627f   // (1/T) * log2(e)
#define LN2F 0.6931471805599453f

typedef short short8 __attribute__((ext_vector_type(8)));
typedef float f32x4  __attribute__((ext_vector_type(4)));
typedef unsigned short us4 __attribute__((ext_vector_type(4)));

static __device__ __forceinline__ unsigned short bf16rne(float f) {
    union { float f; unsigned u; } v; v.f = f;
    unsigned r = (v.u + 0x7FFFu + ((v.u >> 16) & 1u)) >> 16;
    return (unsigned short)r;
}

static __device__ __forceinline__ short8 pack8s(float4 x, float4 y) { // * SCALE
    short8 r;
    r[0]=(short)bf16rne(x.x*SCALE); r[1]=(short)bf16rne(x.y*SCALE);
    r[2]=(short)bf16rne(x.z*SCALE); r[3]=(short)bf16rne(x.w*SCALE);
    r[4]=(short)bf16rne(y.x*SCALE); r[5]=(short)bf16rne(y.y*SCALE);
    r[6]=(short)bf16rne(y.z*SCALE); r[7]=(short)bf16rne(y.w*SCALE);
    return r;
}
static __device__ __forceinline__ short8 pack8(float4 x, float4 y) { // unscaled
    short8 r;
    r[0]=(short)bf16rne(x.x); r[1]=(short)bf16rne(x.y);
    r[2]=(short)bf16rne(x.z); r[3]=(short)bf16rne(x.w);
    r[4]=(short)bf16rne(y.x); r[5]=(short)bf16rne(y.y);
    r[6]=(short)bf16rne(y.z); r[7]=(short)bf16rne(y.w);
    return r;
}

// ---------- K1: conv + histogram + qlabn (blocks 0..511); srr + f2bf (512..515) ----------
__global__ __launch_bounds__(256)
void k1_conv(const float* __restrict__ features, const int* __restrict__ labels,
             const float* __restrict__ queue, const int* __restrict__ queue_labels,
             unsigned short* __restrict__ qbf, int* __restrict__ qlabn,
             unsigned short* __restrict__ f2bf,
             int* __restrict__ cnt, float* __restrict__ srr)
{
    const int blk = blockIdx.x;
    const int t = blk * 256 + threadIdx.x;
    if (blk < 512) {
        if (blk < 256) {
            int lab = (t < BB) ? labels[t] : queue_labels[t - BB];
            qlabn[t] = lab;
            atomicAdd(&cnt[lab], 1);
        }
#pragma unroll
        for (int k = 0; k < 16; ++k) {
            int u = k * 131072 + t;          // us4 index, 2M total
            int e = u * 4;                   // element index
            int row = e >> 7;
            const float* src = (row < BB) ? (features + (size_t)row * 2 * DD + (e & 127))
                                          : (queue + ((size_t)e - (size_t)BB * DD));
            float4 v = *reinterpret_cast<const float4*>(src);
            us4 pk;
            pk[0] = bf16rne(v.x); pk[1] = bf16rne(v.y);
            pk[2] = bf16rne(v.z); pk[3] = bf16rne(v.w);
            *reinterpret_cast<us4*>(qbf + (size_t)e) = pk;
        }
    } else {
        int r = (blk - 512) * 256 + threadIdx.x;     // 0..1023
        const float* f2p = features + (size_t)r * 2 * DD + DD;
        const float* f1p = features + (size_t)r * 2 * DD;
        float d = 0.f;
#pragma unroll
        for (int k = 0; k < DD / 8; ++k) {
            float4 a0 = reinterpret_cast<const float4*>(f2p)[2 * k];
            float4 a1 = reinterpret_cast<const float4*>(f2p)[2 * k + 1];
            float4 b0 = reinterpret_cast<const float4*>(f1p)[2 * k];
            float4 b1 = reinterpret_cast<const float4*>(f1p)[2 * k + 1];
            d += a0.x * b0.x + a0.y * b0.y + a0.z * b0.z + a0.w * b0.w;
            d += a1.x * b1.x + a1.y * b1.y + a1.z * b1.z + a1.w * b1.w;
            *reinterpret_cast<short8*>(f2bf + (size_t)r * DD + k * 8) = pack8s(a0, a1);
        }
        srr[r] = d;
    }
}

// ---------- main: tot/pose/psum via MFMA, stats[col][slice][4] (r5 verbatim) ----------
template<int PRE>
__global__ __launch_bounds__(THREADS)
void supcon_main(const float* __restrict__ features, const int* __restrict__ labels,
                 const float* __restrict__ queue, const int* __restrict__ queue_labels,
                 const unsigned short* __restrict__ qbf, const int* __restrict__ qlabn,
                 const unsigned short* __restrict__ f2bf,
                 float* __restrict__ stats, int nslices)
{
    __shared__ int4 ldsbuf[2][512];   // 2 x 8KB bf16 A-chunks [32][128], swizzled

    const int tid = threadIdx.x;
    const int l = tid & 63, w = tid >> 6;
    const int bid = blockIdx.x;
    const int slice = bid % nslices, f2g = bid / nslices;
    const int sliceRows = QQ / nslices;
    const int nchunks = sliceRows / CHUNK;
    const int colbase = f2g * COLS_PER_BLOCK + w * 64;

    // stationary B operand: 4x16 f2 cols, pre-scaled bf16
    short8 bf[4][4];
    int mylab[4];
#pragma unroll
    for (int b = 0; b < 4; ++b) {
        int r = colbase + b * 16 + (l & 15);
        mylab[b] = labels[r];
        if (PRE) {
            const unsigned short* fp = f2bf + (size_t)r * DD + ((l >> 4) * 8);
#pragma unroll
            for (int kk = 0; kk < 4; ++kk)
                bf[b][kk] = *reinterpret_cast<const short8*>(fp + kk * 32);
        } else {
            const float* fp = features + (size_t)r * 2 * DD + DD + ((l >> 4) * 8);
#pragma unroll
            for (int kk = 0; kk < 4; ++kk) {
                float4 x = *reinterpret_cast<const float4*>(fp + kk * 32);
                float4 y = *reinterpret_cast<const float4*>(fp + kk * 32 + 4);
                bf[b][kk] = pack8s(x, y);
            }
        }
    }

    float tot[4]  = {0.f,0.f,0.f,0.f};
    float pose[4] = {0.f,0.f,0.f,0.f};
    float psum[4] = {0.f,0.f,0.f,0.f};

    const int srow = tid >> 3, sseg = tid & 7;
    const int swzs = (srow & 7) << 4;
    const int j0base = slice * sliceRows;

    // prologue: stage chunk 0
    {
        int j = j0base + srow;
        char* base = (char*)&ldsbuf[0][0] + srow * 256;
        int cb0 = (sseg * 32) ^ swzs;
        if (PRE) {
            const short8* src = reinterpret_cast<const short8*>(
                qbf + (size_t)j * DD + sseg * 16);
            *reinterpret_cast<short8*>(base + cb0)        = src[0];
            *reinterpret_cast<short8*>(base + (cb0 ^ 16)) = src[1];
        } else {
            const float* src = ((j < BB) ? (features + (size_t)j * 2 * DD)
                                         : (queue + (size_t)(j - BB) * DD)) + sseg * 16;
            float4 p0 = reinterpret_cast<const float4*>(src)[0];
            float4 p1 = reinterpret_cast<const float4*>(src)[1];
            float4 p2 = reinterpret_cast<const float4*>(src)[2];
            float4 p3 = reinterpret_cast<const float4*>(src)[3];
            *reinterpret_cast<short8*>(base + cb0)        = pack8(p0, p1);
            *reinterpret_cast<short8*>(base + (cb0 ^ 16)) = pack8(p2, p3);
        }
    }

    int cur = 0;
    for (int c = 0; c < nchunks; ++c) {
        __syncthreads();
        const int cj0 = j0base + c * CHUNK;
        const bool havenext = (c + 1 < nchunks);

        // issue next chunk's loads early (T14)
        short8 nlo, nhi;
        float4 p0, p1, p2, p3;
        if (havenext) {
            int j = cj0 + CHUNK + srow;
            if (PRE) {
                const short8* src = reinterpret_cast<const short8*>(
                    qbf + (size_t)j * DD + sseg * 16);
                nlo = src[0]; nhi = src[1];
            } else {
                const float* src = ((j < BB) ? (features + (size_t)j * 2 * DD)
                                             : (queue + (size_t)(j - BB) * DD)) + sseg * 16;
                p0 = reinterpret_cast<const float4*>(src)[0];
                p1 = reinterpret_cast<const float4*>(src)[1];
                p2 = reinterpret_cast<const float4*>(src)[2];
                p3 = reinterpret_cast<const float4*>(src)[3];
            }
        }

        // compute from buf[cur]
        const char* abase = (const char*)&ldsbuf[cur][0];
#pragma unroll
        for (int t2 = 0; t2 < 2; ++t2) {
            const int row = t2 * 16 + (l & 15);
            const char* rbase = abase + row * 256;
            const int g16 = (l >> 4) * 16;
            const int swz = (row & 7) << 4;
            const int j0 = cj0 + t2 * 16 + ((l >> 4) << 2);

            int4 ql4;
            if (PRE) ql4 = *reinterpret_cast<const int4*>(qlabn + j0);
            else ql4 = (j0 < BB) ? *reinterpret_cast<const int4*>(labels + j0)
                                 : *reinterpret_cast<const int4*>(queue_labels + (j0 - BB));
            const int* ql = reinterpret_cast<const int*>(&ql4);

            f32x4 acc[4];
#pragma unroll
            for (int b = 0; b < 4; ++b) acc[b] = f32x4{0.f,0.f,0.f,0.f};
#pragma unroll
            for (int kk = 0; kk < 4; ++kk) {
                short8 a = *reinterpret_cast<const short8*>(rbase + ((kk * 64 + g16) ^ swz));
#pragma unroll
                for (int b = 0; b < 4; ++b)
                    acc[b] = __builtin_amdgcn_mfma_f32_16x16x32_bf16(a, bf[b][kk], acc[b], 0, 0, 0);
            }
#pragma unroll
            for (int b = 0; b < 4; ++b) {
#pragma unroll
                for (int reg = 0; reg < 4; ++reg) {
                    float a = acc[b][reg];
                    float e = exp2f(a);                 // a = s * log2(e)
                    bool pos = (ql[reg] == mylab[b]);
                    tot[b]  += e;
                    pose[b] += pos ? e : 0.f;
                    psum[b] += pos ? a : 0.f;
                }
            }
        }

        // write next chunk into other buffer
        if (havenext) {
            char* base = (char*)&ldsbuf[cur ^ 1][0] + srow * 256;
            int cb0 = (sseg * 32) ^ swzs;
            if (PRE) {
                *reinterpret_cast<short8*>(base + cb0)        = nlo;
                *reinterpret_cast<short8*>(base + (cb0 ^ 16)) = nhi;
            } else {
                *reinterpret_cast<short8*>(base + cb0)        = pack8(p0, p1);
                *reinterpret_cast<short8*>(base + (cb0 ^ 16)) = pack8(p2, p3);
            }
            cur ^= 1;
        }
    }

#pragma unroll
    for (int b = 0; b < 4; ++b) {
#pragma unroll
        for (int off = 16; off <= 32; off <<= 1) {
            tot[b]  += __shfl_xor(tot[b],  off);
            pose[b] += __shfl_xor(pose[b], off);
            psum[b] += __shfl_xor(psum[b], off);
        }
    }
    if ((l >> 4) == 0) {
#pragma unroll
        for (int b = 0; b < 4; ++b) {
            float4 v; v.x = tot[b]; v.y = pose[b]; v.z = psum[b]; v.w = 0.f;
            *reinterpret_cast<float4*>(
                stats + ((size_t)(colbase + b * 16 + l) * nslices + slice) * 4) = v;
        }
    }
}

// ---------- F1: per-row finish (log terms), accumulate scalars ----------
__global__ __launch_bounds__(256)
void f1_rows(const float* __restrict__ stats, const float* __restrict__ srr,
             const int* __restrict__ cnt, const int* __restrict__ labels,
             float* __restrict__ accums, int nslices)
{
    __shared__ float red[4][2];
    int wv = threadIdx.x >> 6, lane = threadIdx.x & 63;
    int r = blockIdx.x * 4 + wv;
    float tot = 0.f, pose = 0.f, ps = 0.f;
    for (int s = lane; s < nslices; s += 64) {
        float4 v = reinterpret_cast<const float4*>(stats)[(size_t)r * nslices + s];
        tot += v.x; pose += v.y; ps += v.z;
    }
#pragma unroll
    for (int off = 32; off > 0; off >>= 1) {
        tot  += __shfl_xor(tot,  off);
        pose += __shfl_xor(pose, off);
        ps   += __shfl_xor(ps,   off);
    }
    if (lane == 0) {
        float neg  = tot - pose;
        float srow = srr[r] * INV_T;           // exact diag logit
        float trip = srow - logf(tot - expf(srow));
        float w    = 1.f / (float)(cnt[labels[r]] - 1);
        float mlpp = (ps * LN2F - srow) * w - logf(neg);
        red[wv][0] = trip; red[wv][1] = mlpp;
    }
    __syncthreads();
    if (threadIdx.x == 0) {
        atomicAdd(&accums[0], red[0][0] + red[1][0] + red[2][0] + red[3][0]);
        atomicAdd(&accums[1], red[0][1] + red[1][1] + red[2][1] + red[3][1]);
    }
}

__global__ void f2_out(const float* __restrict__ accums, float* __restrict__ out)
{
    if (threadIdx.x == 0) {
        float selfl  = -accums[0] / (float)BB;
        float classl = -accums[1] / (float)BB;
        out[0] = 0.5f * (selfl + classl);
        out[1] = selfl;
        out[2] = classl;
    }
}

extern "C" void kernel_launch(void* const* d_in, const int* in_sizes, int n_in,
                              void* d_out, int out_size, void* d_ws, size_t ws_size,
                              hipStream_t stream)
{
    const float* features     = (const float*)d_in[0];
    const int*   labels       = (const int*)  d_in[1];
    const float* queue        = (const float*)d_in[2];
    const int*   queue_labels = (const int*)  d_in[3];
    char* ws = (char*)d_ws;

    const size_t qbf_sz   = (size_t)QQ * DD * 2;   // 16 MB
    const size_t f2bf_sz  = (size_t)BB * DD * 2;   // 256 KB
    const size_t qlabn_sz = (size_t)QQ * 4;        // 256 KB
    const size_t cnt_sz   = 4096;
    const size_t srr_sz   = 4096;
    const size_t scal_sz  = 256;

    int nslices = NSLICES;
    size_t stats_sz = (size_t)BB * nslices * 16;
    bool pre = ws_size >= qbf_sz + f2bf_sz + qlabn_sz + stats_sz + cnt_sz + srr_sz + scal_sz;
    if (!pre) {
        while ((size_t)BB * nslices * 16 + cnt_sz + srr_sz + scal_sz > ws_size && nslices > 8)
            nslices >>= 1;
        stats_sz = (size_t)BB * nslices * 16;
    }

    size_t off = 0;
    unsigned short* qbf = nullptr; unsigned short* f2bf = nullptr; int* qlabn = nullptr;
    if (pre) {
        qbf   = (unsigned short*)(ws + off); off += qbf_sz;
        f2bf  = (unsigned short*)(ws + off); off += f2bf_sz;
        qlabn = (int*)(ws + off);            off += qlabn_sz;
    }
    float* stats = (float*)(ws + off); off += stats_sz;
    int*   cnt   = (int*)(ws + off);   off += cnt_sz;
    float* scal  = (float*)(ws + off); off += scal_sz;   // [0]=accT, [1]=accM
    float* srr   = (float*)(ws + off); off += srr_sz;

    hipMemsetAsync((void*)cnt, 0, cnt_sz + scal_sz, stream);

    if (pre) {
        k1_conv<<<dim3(516), dim3(256), 0, stream>>>(
            features, labels, queue, queue_labels, qbf, qlabn, f2bf, cnt, srr);
        supcon_main<1><<<dim3(F2G * nslices), dim3(THREADS), 0, stream>>>(
            features, labels, queue, queue_labels, qbf, qlabn, f2bf, stats, nslices);
    } else {
        // fallback: no prebuffers; histogram+srr only (f2bf=null handled by PRE=0 path)
        k1_conv<<<dim3(516), dim3(256), 0, stream>>>(
            features, labels, queue, queue_labels,
            (unsigned short*)(ws), (int*)(ws), (unsigned short*)(ws), cnt, srr);
        supcon_main<0><<<dim3(F2G * nslices), dim3(THREADS), 0, stream>>>(
            features, labels, queue, queue_labels, nullptr, nullptr, nullptr, stats, nslices);
    }

    f1_rows<<<dim3(BB / 4), dim3(256), 0, stream>>>(stats, srr, cnt, labels, scal, nslices);
    f2_out<<<dim3(1), dim3(64), 0, stream>>>(scal, (float*)d_out);
}

// Round 13
// 85.064 us; speedup vs baseline: 1.5536x; 1.1561x over previous
//
#include <hip/hip_runtime.h>
#include <math.h>

#define BB 1024
#define DD 128
#define QQ 65536
#define CHUNK 32
#define THREADS 256
#define COLS_PER_BLOCK 256
#define F2G (BB / COLS_PER_BLOCK)   // 4
#define NSLICES 256
#define INV_T 14.285714285714286f
#define SCALE 20.609929155556627f   // (1/T) * log2(e)
#define LN2F 0.6931471805599453f

typedef short short8 __attribute__((ext_vector_type(8)));
typedef float f32x4  __attribute__((ext_vector_type(4)));
typedef unsigned short us4 __attribute__((ext_vector_type(4)));

#if __has_builtin(__builtin_amdgcn_exp2f)
#define EXP2F(x) __builtin_amdgcn_exp2f(x)
#else
#define EXP2F(x) exp2f(x)
#endif

static __device__ __forceinline__ unsigned short bf16rne(float f) {
    union { float f; unsigned u; } v; v.f = f;
    unsigned r = (v.u + 0x7FFFu + ((v.u >> 16) & 1u)) >> 16;
    return (unsigned short)r;
}

static __device__ __forceinline__ short8 pack8s(float4 x, float4 y) { // * SCALE
    short8 r;
    r[0]=(short)bf16rne(x.x*SCALE); r[1]=(short)bf16rne(x.y*SCALE);
    r[2]=(short)bf16rne(x.z*SCALE); r[3]=(short)bf16rne(x.w*SCALE);
    r[4]=(short)bf16rne(y.x*SCALE); r[5]=(short)bf16rne(y.y*SCALE);
    r[6]=(short)bf16rne(y.z*SCALE); r[7]=(short)bf16rne(y.w*SCALE);
    return r;
}
static __device__ __forceinline__ short8 pack8(float4 x, float4 y) { // unscaled
    short8 r;
    r[0]=(short)bf16rne(x.x); r[1]=(short)bf16rne(x.y);
    r[2]=(short)bf16rne(x.z); r[3]=(short)bf16rne(x.w);
    r[4]=(short)bf16rne(y.x); r[5]=(short)bf16rne(y.y);
    r[6]=(short)bf16rne(y.z); r[7]=(short)bf16rne(y.w);
    return r;
}

// ---------- K1: conv + histogram + qlabn (blocks 0..511); srr + f2bf (512..515) ----------
__global__ __launch_bounds__(256)
void k1_conv(const float* __restrict__ features, const int* __restrict__ labels,
             const float* __restrict__ queue, const int* __restrict__ queue_labels,
             unsigned short* __restrict__ qbf, int* __restrict__ qlabn,
             unsigned short* __restrict__ f2bf,
             int* __restrict__ cnt, float* __restrict__ srr)
{
    const int blk = blockIdx.x;
    const int t = blk * 256 + threadIdx.x;
    if (blk < 512) {
        if (blk < 256) {
            int lab = (t < BB) ? labels[t] : queue_labels[t - BB];
            qlabn[t] = lab;
            atomicAdd(&cnt[lab], 1);
        }
#pragma unroll
        for (int k = 0; k < 16; ++k) {
            int u = k * 131072 + t;          // us4 index, 2M total
            int e = u * 4;                   // element index
            int row = e >> 7;
            const float* src = (row < BB) ? (features + (size_t)row * 2 * DD + (e & 127))
                                          : (queue + ((size_t)e - (size_t)BB * DD));
            float4 v = *reinterpret_cast<const float4*>(src);
            us4 pk;
            pk[0] = bf16rne(v.x); pk[1] = bf16rne(v.y);
            pk[2] = bf16rne(v.z); pk[3] = bf16rne(v.w);
            *reinterpret_cast<us4*>(qbf + (size_t)e) = pk;
        }
    } else {
        int r = (blk - 512) * 256 + threadIdx.x;     // 0..1023
        const float* f2p = features + (size_t)r * 2 * DD + DD;
        const float* f1p = features + (size_t)r * 2 * DD;
        float d = 0.f;
#pragma unroll
        for (int k = 0; k < DD / 8; ++k) {
            float4 a0 = reinterpret_cast<const float4*>(f2p)[2 * k];
            float4 a1 = reinterpret_cast<const float4*>(f2p)[2 * k + 1];
            float4 b0 = reinterpret_cast<const float4*>(f1p)[2 * k];
            float4 b1 = reinterpret_cast<const float4*>(f1p)[2 * k + 1];
            d += a0.x * b0.x + a0.y * b0.y + a0.z * b0.z + a0.w * b0.w;
            d += a1.x * b1.x + a1.y * b1.y + a1.z * b1.z + a1.w * b1.w;
            *reinterpret_cast<short8*>(f2bf + (size_t)r * DD + k * 8) = pack8s(a0, a1);
        }
        srr[r] = d;
    }
}

// ---------- main: r12 verbatim except exp2f -> EXP2F intrinsic ----------
template<int PRE>
__global__ __launch_bounds__(THREADS)
void supcon_main(const float* __restrict__ features, const int* __restrict__ labels,
                 const float* __restrict__ queue, const int* __restrict__ queue_labels,
                 const unsigned short* __restrict__ qbf, const int* __restrict__ qlabn,
                 const unsigned short* __restrict__ f2bf,
                 float* __restrict__ stats, int nslices)
{
    __shared__ int4 ldsbuf[2][512];   // 2 x 8KB bf16 A-chunks [32][128], swizzled

    const int tid = threadIdx.x;
    const int l = tid & 63, w = tid >> 6;
    const int bid = blockIdx.x;
    const int slice = bid % nslices, f2g = bid / nslices;
    const int sliceRows = QQ / nslices;
    const int nchunks = sliceRows / CHUNK;
    const int colbase = f2g * COLS_PER_BLOCK + w * 64;

    // stationary B operand: 4x16 f2 cols, pre-scaled bf16
    short8 bf[4][4];
    int mylab[4];
#pragma unroll
    for (int b = 0; b < 4; ++b) {
        int r = colbase + b * 16 + (l & 15);
        mylab[b] = labels[r];
        if (PRE) {
            const unsigned short* fp = f2bf + (size_t)r * DD + ((l >> 4) * 8);
#pragma unroll
            for (int kk = 0; kk < 4; ++kk)
                bf[b][kk] = *reinterpret_cast<const short8*>(fp + kk * 32);
        } else {
            const float* fp = features + (size_t)r * 2 * DD + DD + ((l >> 4) * 8);
#pragma unroll
            for (int kk = 0; kk < 4; ++kk) {
                float4 x = *reinterpret_cast<const float4*>(fp + kk * 32);
                float4 y = *reinterpret_cast<const float4*>(fp + kk * 32 + 4);
                bf[b][kk] = pack8s(x, y);
            }
        }
    }

    float tot[4]  = {0.f,0.f,0.f,0.f};
    float pose[4] = {0.f,0.f,0.f,0.f};
    float psum[4] = {0.f,0.f,0.f,0.f};

    const int srow = tid >> 3, sseg = tid & 7;
    const int swzs = (srow & 7) << 4;
    const int j0base = slice * sliceRows;

    // prologue: stage chunk 0
    {
        int j = j0base + srow;
        char* base = (char*)&ldsbuf[0][0] + srow * 256;
        int cb0 = (sseg * 32) ^ swzs;
        if (PRE) {
            const short8* src = reinterpret_cast<const short8*>(
                qbf + (size_t)j * DD + sseg * 16);
            *reinterpret_cast<short8*>(base + cb0)        = src[0];
            *reinterpret_cast<short8*>(base + (cb0 ^ 16)) = src[1];
        } else {
            const float* src = ((j < BB) ? (features + (size_t)j * 2 * DD)
                                         : (queue + (size_t)(j - BB) * DD)) + sseg * 16;
            float4 p0 = reinterpret_cast<const float4*>(src)[0];
            float4 p1 = reinterpret_cast<const float4*>(src)[1];
            float4 p2 = reinterpret_cast<const float4*>(src)[2];
            float4 p3 = reinterpret_cast<const float4*>(src)[3];
            *reinterpret_cast<short8*>(base + cb0)        = pack8(p0, p1);
            *reinterpret_cast<short8*>(base + (cb0 ^ 16)) = pack8(p2, p3);
        }
    }

    int cur = 0;
    for (int c = 0; c < nchunks; ++c) {
        __syncthreads();
        const int cj0 = j0base + c * CHUNK;
        const bool havenext = (c + 1 < nchunks);

        // issue next chunk's loads early (T14)
        short8 nlo, nhi;
        float4 p0, p1, p2, p3;
        if (havenext) {
            int j = cj0 + CHUNK + srow;
            if (PRE) {
                const short8* src = reinterpret_cast<const short8*>(
                    qbf + (size_t)j * DD + sseg * 16);
                nlo = src[0]; nhi = src[1];
            } else {
                const float* src = ((j < BB) ? (features + (size_t)j * 2 * DD)
                                             : (queue + (size_t)(j - BB) * DD)) + sseg * 16;
                p0 = reinterpret_cast<const float4*>(src)[0];
                p1 = reinterpret_cast<const float4*>(src)[1];
                p2 = reinterpret_cast<const float4*>(src)[2];
                p3 = reinterpret_cast<const float4*>(src)[3];
            }
        }

        // compute from buf[cur]
        const char* abase = (const char*)&ldsbuf[cur][0];
#pragma unroll
        for (int t2 = 0; t2 < 2; ++t2) {
            const int row = t2 * 16 + (l & 15);
            const char* rbase = abase + row * 256;
            const int g16 = (l >> 4) * 16;
            const int swz = (row & 7) << 4;
            const int j0 = cj0 + t2 * 16 + ((l >> 4) << 2);

            int4 ql4;
            if (PRE) ql4 = *reinterpret_cast<const int4*>(qlabn + j0);
            else ql4 = (j0 < BB) ? *reinterpret_cast<const int4*>(labels + j0)
                                 : *reinterpret_cast<const int4*>(queue_labels + (j0 - BB));
            const int* ql = reinterpret_cast<const int*>(&ql4);

            f32x4 acc[4];
#pragma unroll
            for (int b = 0; b < 4; ++b) acc[b] = f32x4{0.f,0.f,0.f,0.f};
#pragma unroll
            for (int kk = 0; kk < 4; ++kk) {
                short8 a = *reinterpret_cast<const short8*>(rbase + ((kk * 64 + g16) ^ swz));
#pragma unroll
                for (int b = 0; b < 4; ++b)
                    acc[b] = __builtin_amdgcn_mfma_f32_16x16x32_bf16(a, bf[b][kk], acc[b], 0, 0, 0);
            }
#pragma unroll
            for (int b = 0; b < 4; ++b) {
#pragma unroll
                for (int reg = 0; reg < 4; ++reg) {
                    float a = acc[b][reg];
                    float e = EXP2F(a);                 // a = s * log2(e); |a| <= ~20.6
                    bool pos = (ql[reg] == mylab[b]);
                    tot[b]  += e;
                    pose[b] += pos ? e : 0.f;
                    psum[b] += pos ? a : 0.f;
                }
            }
        }

        // write next chunk into other buffer
        if (havenext) {
            char* base = (char*)&ldsbuf[cur ^ 1][0] + srow * 256;
            int cb0 = (sseg * 32) ^ swzs;
            if (PRE) {
                *reinterpret_cast<short8*>(base + cb0)        = nlo;
                *reinterpret_cast<short8*>(base + (cb0 ^ 16)) = nhi;
            } else {
                *reinterpret_cast<short8*>(base + cb0)        = pack8(p0, p1);
                *reinterpret_cast<short8*>(base + (cb0 ^ 16)) = pack8(p2, p3);
            }
            cur ^= 1;
        }
    }

#pragma unroll
    for (int b = 0; b < 4; ++b) {
#pragma unroll
        for (int off = 16; off <= 32; off <<= 1) {
            tot[b]  += __shfl_xor(tot[b],  off);
            pose[b] += __shfl_xor(pose[b], off);
            psum[b] += __shfl_xor(psum[b], off);
        }
    }
    if ((l >> 4) == 0) {
#pragma unroll
        for (int b = 0; b < 4; ++b) {
            float4 v; v.x = tot[b]; v.y = pose[b]; v.z = psum[b]; v.w = 0.f;
            *reinterpret_cast<float4*>(
                stats + ((size_t)(colbase + b * 16 + l) * nslices + slice) * 4) = v;
        }
    }
}

// ---------- F1: per-row finish + ticketed final output (merged f2) ----------
__global__ __launch_bounds__(256)
void f1_rows(const float* __restrict__ stats, const float* __restrict__ srr,
             const int* __restrict__ cnt, const int* __restrict__ labels,
             float* __restrict__ accums, int* __restrict__ ticket,
             float* __restrict__ out, int nslices)
{
    __shared__ float red[4][2];
    int wv = threadIdx.x >> 6, lane = threadIdx.x & 63;
    int r = blockIdx.x * 4 + wv;
    float tot = 0.f, pose = 0.f, ps = 0.f;
    for (int s = lane; s < nslices; s += 64) {
        float4 v = reinterpret_cast<const float4*>(stats)[(size_t)r * nslices + s];
        tot += v.x; pose += v.y; ps += v.z;
    }
#pragma unroll
    for (int off = 32; off > 0; off >>= 1) {
        tot  += __shfl_xor(tot,  off);
        pose += __shfl_xor(pose, off);
        ps   += __shfl_xor(ps,   off);
    }
    if (lane == 0) {
        float neg  = tot - pose;
        float srow = srr[r] * INV_T;           // exact diag logit
        float trip = srow - logf(tot - expf(srow));
        float w    = 1.f / (float)(cnt[labels[r]] - 1);
        float mlpp = (ps * LN2F - srow) * w - logf(neg);
        red[wv][0] = trip; red[wv][1] = mlpp;
    }
    __syncthreads();
    if (threadIdx.x == 0) {
        atomicAdd(&accums[0], red[0][0] + red[1][0] + red[2][0] + red[3][0]);
        atomicAdd(&accums[1], red[0][1] + red[1][1] + red[2][1] + red[3][1]);
        __threadfence();
        int old = atomicAdd(ticket, 1);
        if (old == (BB / 4) - 1) {
            float aT = atomicAdd(&accums[0], 0.f);
            float aM = atomicAdd(&accums[1], 0.f);
            float selfl  = -aT / (float)BB;
            float classl = -aM / (float)BB;
            out[0] = 0.5f * (selfl + classl);
            out[1] = selfl;
            out[2] = classl;
        }
    }
}

extern "C" void kernel_launch(void* const* d_in, const int* in_sizes, int n_in,
                              void* d_out, int out_size, void* d_ws, size_t ws_size,
                              hipStream_t stream)
{
    const float* features     = (const float*)d_in[0];
    const int*   labels       = (const int*)  d_in[1];
    const float* queue        = (const float*)d_in[2];
    const int*   queue_labels = (const int*)  d_in[3];
    char* ws = (char*)d_ws;

    const size_t qbf_sz   = (size_t)QQ * DD * 2;   // 16 MB
    const size_t f2bf_sz  = (size_t)BB * DD * 2;   // 256 KB
    const size_t qlabn_sz = (size_t)QQ * 4;        // 256 KB
    const size_t cnt_sz   = 4096;
    const size_t srr_sz   = 4096;
    const size_t scal_sz  = 256;                   // accums + ticket

    int nslices = NSLICES;
    size_t stats_sz = (size_t)BB * nslices * 16;
    bool pre = ws_size >= qbf_sz + f2bf_sz + qlabn_sz + stats_sz + cnt_sz + srr_sz + scal_sz;
    if (!pre) {
        while ((size_t)BB * nslices * 16 + cnt_sz + srr_sz + scal_sz > ws_size && nslices > 8)
            nslices >>= 1;
        stats_sz = (size_t)BB * nslices * 16;
    }

    size_t off = 0;
    unsigned short* qbf = nullptr; unsigned short* f2bf = nullptr; int* qlabn = nullptr;
    if (pre) {
        qbf   = (unsigned short*)(ws + off); off += qbf_sz;
        f2bf  = (unsigned short*)(ws + off); off += f2bf_sz;
        qlabn = (int*)(ws + off);            off += qlabn_sz;
    }
    float* stats  = (float*)(ws + off); off += stats_sz;
    int*   cnt    = (int*)(ws + off);   off += cnt_sz;
    float* scal   = (float*)(ws + off);                  // [0]=accT, [1]=accM
    int*   ticket = (int*)(ws + off + 64);
    off += scal_sz;
    float* srr    = (float*)(ws + off); off += srr_sz;

    hipMemsetAsync((void*)cnt, 0, cnt_sz + scal_sz, stream);

    if (pre) {
        k1_conv<<<dim3(516), dim3(256), 0, stream>>>(
            features, labels, queue, queue_labels, qbf, qlabn, f2bf, cnt, srr);
        supcon_main<1><<<dim3(F2G * nslices), dim3(THREADS), 0, stream>>>(
            features, labels, queue, queue_labels, qbf, qlabn, f2bf, stats, nslices);
    } else {
        k1_conv<<<dim3(516), dim3(256), 0, stream>>>(
            features, labels, queue, queue_labels,
            (unsigned short*)(ws), (int*)(ws), (unsigned short*)(ws), cnt, srr);
        supcon_main<0><<<dim3(F2G * nslices), dim3(THREADS), 0, stream>>>(
            features, labels, queue, queue_labels, nullptr, nullptr, nullptr, stats, nslices);
    }

    f1_rows<<<dim3(BB / 4), dim3(256), 0, stream>>>(
        stats, srr, cnt, labels, scal, ticket, (float*)d_out, nslices);
}